// Round 4
// baseline (68.336 us; speedup 1.0000x reference)
//
#include <hip/hip_runtime.h>
#include <hip/hip_fp16.h>

// Problem constants (match reference)
#define N_NODES  4096
#define MAX_PATH 5
#define EDGE_DIM 16

typedef int iv2 __attribute__((ext_vector_type(2)));

// Phase 1: precompute D[l][e] = dot(edge_attr[e], edge_vector[l]) in fp16.
// Table = 5*100K*2B = 1 MB -> comfortably L2-resident per XCD even with
// streaming traffic, provided the streams are marked non-temporal.
__global__ __launch_bounds__(256) void precompute_dots_kernel(
    const float* __restrict__ edge_attr,   // [E, 16]
    const float* __restrict__ edge_vector, // [MAX_PATH, 16]
    __half*      __restrict__ D,           // [MAX_PATH, E] fp16
    int n_edges)
{
    int e = blockIdx.x * blockDim.x + threadIdx.x;
    if (e >= n_edges) return;

    const float4* ea = (const float4*)(edge_attr + (size_t)e * EDGE_DIM);
    float4 a0 = ea[0], a1 = ea[1], a2 = ea[2], a3 = ea[3];

#pragma unroll
    for (int l = 0; l < MAX_PATH; ++l) {
        const float4* ev = (const float4*)(edge_vector + l * EDGE_DIM);
        float4 b0 = ev[0], b1 = ev[1], b2 = ev[2], b3 = ev[3];
        float d = a0.x*b0.x + a0.y*b0.y + a0.z*b0.z + a0.w*b0.w
                + a1.x*b1.x + a1.y*b1.y + a1.z*b1.z + a1.w*b1.w
                + a2.x*b2.x + a2.y*b2.y + a2.z*b2.z + a2.w*b2.w
                + a3.x*b3.x + a3.y*b3.y + a3.z*b3.z + a3.w*b3.w;
        D[(size_t)l * n_edges + e] = __float2half(d);
    }
}

// Phase 2: 2 pairs/thread. Index streams and scatter store are NON-TEMPORAL
// (don't evict the hot D table from L2); D gathers are regular cached loads.
__global__ __launch_bounds__(256) void edge_encoding_kernel(
    const __half* __restrict__ D,        // [MAX_PATH, E]
    const int*    __restrict__ src_idx,  // [P]
    const int*    __restrict__ dst_idx,  // [P]
    const int*    __restrict__ path_idx, // [P, MAX_PATH]
    float*        __restrict__ out,      // [N_NODES, N_NODES]
    int n_pairs, int n_edges)
{
    int t  = blockIdx.x * blockDim.x + threadIdx.x;
    int p0 = t * 2;
    if (p0 >= n_pairs) return;

    if (p0 + 1 < n_pairs) {
        // 10 path ints for 2 pairs = 5 x 8B nt loads (8B-aligned: p0 even).
        const iv2* pp = (const iv2*)(path_idx + (size_t)p0 * MAX_PATH);
        iv2 w0 = __builtin_nontemporal_load(pp + 0);
        iv2 w1 = __builtin_nontemporal_load(pp + 1);
        iv2 w2 = __builtin_nontemporal_load(pp + 2);
        iv2 w3 = __builtin_nontemporal_load(pp + 3);
        iv2 w4 = __builtin_nontemporal_load(pp + 4);
        int e[10] = { w0.x, w0.y, w1.x, w1.y, w2.x,
                      w2.y, w3.x, w3.y, w4.x, w4.y };

        // Issue all 10 independent gathers (L2-hot D) before any use.
        float g[10];
#pragma unroll
        for (int j = 0; j < 2; ++j) {
#pragma unroll
            for (int l = 0; l < MAX_PATH; ++l) {
                int idx = e[j * MAX_PATH + l];
                g[j * MAX_PATH + l] =
                    (idx >= 0) ? __half2float(D[(size_t)l * n_edges + idx]) : 0.0f;
            }
        }

        iv2 sv = __builtin_nontemporal_load((const iv2*)(src_idx + p0));
        iv2 dv = __builtin_nontemporal_load((const iv2*)(dst_idx + p0));
        int srcs[2] = { sv.x, sv.y };
        int dsts[2] = { dv.x, dv.y };

#pragma unroll
        for (int j = 0; j < 2; ++j) {
            float sum = 0.0f;
            int   cnt = 0;
#pragma unroll
            for (int l = 0; l < MAX_PATH; ++l) {
                if (e[j * MAX_PATH + l] >= 0) { sum += g[j * MAX_PATH + l]; ++cnt; }
            }
            float val = (cnt > 0) ? (sum / (float)cnt) : 0.0f;
            __builtin_nontemporal_store(val, out + (size_t)srcs[j] * N_NODES + dsts[j]);
        }
    } else {
        // Tail (not taken for even n_pairs).
        for (int p = p0; p < n_pairs; ++p) {
            float sum = 0.0f;
            int   cnt = 0;
#pragma unroll
            for (int l = 0; l < MAX_PATH; ++l) {
                int idx = path_idx[(size_t)p * MAX_PATH + l];
                if (idx >= 0) { sum += __half2float(D[(size_t)l * n_edges + idx]); ++cnt; }
            }
            float val = (cnt > 0) ? (sum / (float)cnt) : 0.0f;
            __builtin_nontemporal_store(val, out + (size_t)src_idx[p] * N_NODES + dst_idx[p]);
        }
    }
}

extern "C" void kernel_launch(void* const* d_in, const int* in_sizes, int n_in,
                              void* d_out, int out_size, void* d_ws, size_t ws_size,
                              hipStream_t stream)
{
    // Input order: x, edge_attr, edge_vector, src_idx, dst_idx, path_idx
    const float* edge_attr   = (const float*)d_in[1];
    const float* edge_vector = (const float*)d_in[2];
    const int*   src_idx     = (const int*)d_in[3];
    const int*   dst_idx     = (const int*)d_in[4];
    const int*   path_idx    = (const int*)d_in[5];
    float*       out         = (float*)d_out;
    __half*      D           = (__half*)d_ws;   // 5 * n_edges * 2B = 1 MB

    const int n_edges = in_sizes[1] / EDGE_DIM;  // 100,000
    const int n_pairs = in_sizes[3];             // 1,000,000

    hipMemsetAsync(d_out, 0, (size_t)out_size * sizeof(float), stream);

    const int block = 256;
    precompute_dots_kernel<<<(n_edges + block - 1) / block, block, 0, stream>>>(
        edge_attr, edge_vector, D, n_edges);

    const int threads_needed = (n_pairs + 1) / 2;
    edge_encoding_kernel<<<(threads_needed + block - 1) / block, block, 0, stream>>>(
        D, src_idx, dst_idx, path_idx, out, n_pairs, n_edges);
}

// Round 5
// 51.748 us; speedup vs baseline: 1.3206x; 1.3206x over previous
//
#include <hip/hip_runtime.h>

// Problem constants (match reference)
#define N_NODES  4096
#define MAX_PATH 5
#define EDGE_DIM 16

typedef int   iv2 __attribute__((ext_vector_type(2)));
typedef float fv2 __attribute__((ext_vector_type(2)));

// Phase 0: precompute D[l][e] = dot(edge_attr[e], edge_vector[l]) (f32).
// 2 MB table -> L2-resident during phase A (no store traffic to thrash it).
__global__ __launch_bounds__(256) void precompute_dots_kernel(
    const float* __restrict__ edge_attr,   // [E, 16]
    const float* __restrict__ edge_vector, // [MAX_PATH, 16]
    float*       __restrict__ D,           // [MAX_PATH, E]
    int n_edges)
{
    int e = blockIdx.x * blockDim.x + threadIdx.x;
    if (e >= n_edges) return;

    const float4* ea = (const float4*)(edge_attr + (size_t)e * EDGE_DIM);
    float4 a0 = ea[0], a1 = ea[1], a2 = ea[2], a3 = ea[3];

#pragma unroll
    for (int l = 0; l < MAX_PATH; ++l) {
        const float4* ev = (const float4*)(edge_vector + l * EDGE_DIM);
        float4 b0 = ev[0], b1 = ev[1], b2 = ev[2], b3 = ev[3];
        float d = a0.x*b0.x + a0.y*b0.y + a0.z*b0.z + a0.w*b0.w
                + a1.x*b1.x + a1.y*b1.y + a1.z*b1.z + a1.w*b1.w
                + a2.x*b2.x + a2.y*b2.y + a2.z*b2.z + a2.w*b2.w
                + a3.x*b3.x + a3.y*b3.y + a3.z*b3.z + a3.w*b3.w;
        D[(size_t)l * n_edges + e] = d;
    }
}

// Phase A: gather-only. 2 pairs/thread: int2 path loads, up to 10 independent
// L2-resident gathers, mean, COALESCED write of vals[p]. No random stores here.
__global__ __launch_bounds__(256) void gather_vals_kernel(
    const float* __restrict__ D,        // [MAX_PATH, E]
    const int*   __restrict__ path_idx, // [P, MAX_PATH]
    float*       __restrict__ vals,     // [P]
    int n_pairs, int n_edges)
{
    int t  = blockIdx.x * blockDim.x + threadIdx.x;
    int p0 = t * 2;
    if (p0 >= n_pairs) return;

    // 10 path ints for 2 pairs = 5 aligned 8B loads.
    const iv2* pp = (const iv2*)(path_idx + (size_t)p0 * MAX_PATH);
    iv2 w0 = pp[0], w1 = pp[1], w2 = pp[2], w3 = pp[3], w4 = pp[4];
    int e[10] = { w0.x, w0.y, w1.x, w1.y, w2.x,
                  w2.y, w3.x, w3.y, w4.x, w4.y };

    float g[10];
#pragma unroll
    for (int j = 0; j < 2; ++j) {
#pragma unroll
        for (int l = 0; l < MAX_PATH; ++l) {
            int idx = e[j * MAX_PATH + l];
            g[j * MAX_PATH + l] = (idx >= 0) ? D[(size_t)l * n_edges + idx] : 0.0f;
        }
    }

    fv2 v;
#pragma unroll
    for (int j = 0; j < 2; ++j) {
        float sum = 0.0f;
        int   cnt = 0;
#pragma unroll
        for (int l = 0; l < MAX_PATH; ++l) {
            if (e[j * MAX_PATH + l] >= 0) { sum += g[j * MAX_PATH + l]; ++cnt; }
        }
        v[j] = (cnt > 0) ? (sum / (float)cnt) : 0.0f;
    }
    *(fv2*)(vals + p0) = v;   // coalesced 8B store
}

// Phase B: scatter-only. 4 pairs/thread: coalesced float4/int4 reads,
// 4 random stores. The only random traffic in this kernel.
__global__ __launch_bounds__(256) void scatter_vals_kernel(
    const float* __restrict__ vals,     // [P]
    const int*   __restrict__ src_idx,  // [P]
    const int*   __restrict__ dst_idx,  // [P]
    float*       __restrict__ out,      // [N_NODES, N_NODES]
    int n_pairs)
{
    int t  = blockIdx.x * blockDim.x + threadIdx.x;
    int p0 = t * 4;
    if (p0 >= n_pairs) return;

    if (p0 + 3 < n_pairs) {
        float4 v  = *(const float4*)(vals + p0);
        int4   sv = *(const int4*)(src_idx + p0);
        int4   dv = *(const int4*)(dst_idx + p0);
        out[(size_t)sv.x * N_NODES + dv.x] = v.x;
        out[(size_t)sv.y * N_NODES + dv.y] = v.y;
        out[(size_t)sv.z * N_NODES + dv.z] = v.z;
        out[(size_t)sv.w * N_NODES + dv.w] = v.w;
    } else {
        for (int p = p0; p < n_pairs; ++p)
            out[(size_t)src_idx[p] * N_NODES + dst_idx[p]] = vals[p];
    }
}

extern "C" void kernel_launch(void* const* d_in, const int* in_sizes, int n_in,
                              void* d_out, int out_size, void* d_ws, size_t ws_size,
                              hipStream_t stream)
{
    // Input order: x, edge_attr, edge_vector, src_idx, dst_idx, path_idx
    const float* edge_attr   = (const float*)d_in[1];
    const float* edge_vector = (const float*)d_in[2];
    const int*   src_idx     = (const int*)d_in[3];
    const int*   dst_idx     = (const int*)d_in[4];
    const int*   path_idx    = (const int*)d_in[5];
    float*       out         = (float*)d_out;

    const int n_edges = in_sizes[1] / EDGE_DIM;  // 100,000
    const int n_pairs = in_sizes[3];             // 1,000,000

    float* D    = (float*)d_ws;                         // 5*E*4B = 2 MB
    float* vals = (float*)((char*)d_ws + ((size_t)5 * n_edges * sizeof(float) + 1023 & ~(size_t)1023));

    hipMemsetAsync(d_out, 0, (size_t)out_size * sizeof(float), stream);

    const int block = 256;
    precompute_dots_kernel<<<(n_edges + block - 1) / block, block, 0, stream>>>(
        edge_attr, edge_vector, D, n_edges);

    const int tA = (n_pairs + 1) / 2;
    gather_vals_kernel<<<(tA + block - 1) / block, block, 0, stream>>>(
        D, path_idx, vals, n_pairs, n_edges);

    const int tB = (n_pairs + 3) / 4;
    scatter_vals_kernel<<<(tB + block - 1) / block, block, 0, stream>>>(
        vals, src_idx, dst_idx, out, n_pairs);
}